// Round 6
// baseline (261.726 us; speedup 1.0000x reference)
//
#include <hip/hip_runtime.h>
#include <hip/hip_bf16.h>

#define RD 64
#define UD 64
#define VD 64
#define HD 128
#define XD 64
#define NB 8
#define SITES 1024

typedef float f32x4 __attribute__((ext_vector_type(4)));
typedef float f32x2 __attribute__((ext_vector_type(2)));
typedef __bf16 bf16x4 __attribute__((ext_vector_type(4)));
typedef __bf16 bf16x8 __attribute__((ext_vector_type(8)));
typedef unsigned int u32x4 __attribute__((ext_vector_type(4)));
typedef unsigned short u16;
typedef unsigned short u16x4 __attribute__((ext_vector_type(4)));

// Raw workgroup barrier WITHOUT the vmcnt(0) drain __syncthreads carries.
// 0xC07F = lgkmcnt(0), vmcnt=63 (open), expcnt=7 (open) on gfx9-lineage.
__device__ __forceinline__ void lds_barrier() {
  __builtin_amdgcn_s_waitcnt(0xC07F);
  __builtin_amdgcn_s_barrier();
}

// global -> LDS direct copy, 16 B per lane; LDS dest = wave-uniform base + lane*16
#define GLOAD_LDS(g, l)                                                   \
  __builtin_amdgcn_global_load_lds(                                       \
      (const __attribute__((address_space(1))) void*)(g),                 \
      (__attribute__((address_space(3))) void*)(l), 16, 0, 0)

// ---------------- kprep: all three input transforms in one launch ----------------
// b < 256   : w2 [x][r][h] fp32 -> w2t bf16 [r][x][h]
// b < 384   : r  [n][s][r] fp32 -> rt fp32 [n][r][s]
// else      : u  [n][r][u][v] fp32 -> ut fp32 [r][u][v][n]   (2048 blocks)
__global__ void kprep(const float* __restrict__ w2, u16* __restrict__ w2t,
                      const float* __restrict__ r, float* __restrict__ rt,
                      const float* __restrict__ u, float* __restrict__ ut) {
  __shared__ float tl[64][68];
  int b = blockIdx.x;
  int t = threadIdx.x;
  if (b < 256) {
    int rr = b >> 2, qq = b & 3;
    for (int i = 0; i < 8; ++i) {
      int idx = qq * 2048 + i * 256 + t;   // (x,h)
      int x = idx >> 7, h = idx & 127;
      float val = w2[((size_t)x * RD + rr) * HD + h];
      __hip_bfloat16 hv = __float2bfloat16(val);
      w2t[((size_t)rr * XD + x) * HD + h] = *(u16*)&hv;
    }
  } else if (b < 384) {
    int bb = b - 256;
    int n = bb >> 4, sb = (bb & 15) * 64;
    for (int i = 0; i < 4; ++i) {
      int flat = i * 256 + t;
      int s = flat >> 4, ch = flat & 15;
      f32x4 d = *(const f32x4*)(r + ((size_t)(n * SITES + sb + s) * RD + ch * 4));
      *(f32x4*)&tl[s][ch * 4] = d;
    }
    __syncthreads();
    for (int i = 0; i < 4; ++i) {
      int flat = i * 256 + t;
      int rr = flat >> 4, ch = flat & 15;
      f32x4 o;
      o.x = tl[ch * 4 + 0][rr];
      o.y = tl[ch * 4 + 1][rr];
      o.z = tl[ch * 4 + 2][rr];
      o.w = tl[ch * 4 + 3][rr];
      *(f32x4*)(rt + ((size_t)(n * RD + rr) * SITES + sb + ch * 4)) = o;
    }
  } else {
    int f = (b - 384) * 256 + t;        // 524288 f32x4 units of ut
    int nh = f & 1, v = (f >> 1) & 63, uu = (f >> 7) & 63, rr = f >> 13;
    f32x4 o;
#pragma unroll
    for (int k = 0; k < 4; ++k)
      o[k] = u[(((size_t)(nh * 4 + k) * RD + rr) * UD + uu) * VD + v];
    *(f32x4*)(ut + (size_t)f * 4) = o;
  }
}

// ---------------- k_a_full v6: gload_lds-staged streaming + LDS compute ---------
// R5 post-mortem: v3/v4/v5 (register-ring FMA coupling) ALL pin at ~2.9 TB/s
// regardless of segment size (128B/256B/8KB), occupancy (4-16 waves/CU), or page
// locality -- while k_a_red-style dedicated load/store kernels hit ~7 TB/s on the
// same data.  Remaining variable: load issue is interleaved with VALU bursts and
// multi-stream vmcnt waits.  v6 decouples them with the proven 2-phase template
// (T3-minimal): per 8-uu chunk, stage 64 KB w1 + 4 KB ut to LDS via width-16
// global_load_lds (linear dest, monotone addresses, no VGPR round-trip), compute
// the PREVIOUS chunk from LDS, one __syncthreads per chunk (its vmcnt(0) drain IS
// the template's wait).  Double-buffered: 136 KB LDS, 1 block/CU.
// Numerics: same sequential uu=0..63 fp32 accumulation per (v,h), single bf16
// round -> bit-identical at.
__global__ __launch_bounds__(256, 1) void k_a_full(const float* __restrict__ w1,
                                                   const float* __restrict__ ut,
                                                   u16* __restrict__ at) {
  // [0..16384)      WB buf0: 8 uu x 16 v x 128 h floats (64 KB)
  // [16384..32768)  WB buf1
  // [32768..33792)  UB buf0: 8 uu x 16 v x 8 n floats (4 KB)
  // [33792..34816)  UB buf1
  // epilogue tile (8*128*17 = 17408 floats) aliases WB region after final sync
  __shared__ __align__(16) float smem[34816];   // 136 KB
  int b = blockIdx.x;                   // 256 = rr(64) x vq(4)
  int rr = b >> 2, vq = b & 3;
  int t = threadIdx.x;                  // 256
  int w = t >> 6, L = t & 63;           // wave, lane
  int vl = t >> 4;                      // v-local (16)
  int hs = t & 15;                      // 16 h-strips x 8 h
  int h0 = hs * 8;

  const float* w1slab = w1 + (size_t)rr * UD * VD * HD + (size_t)vq * 16 * HD;
  const float* utslab = ut + (size_t)rr * UD * VD * NB + (size_t)vq * 16 * NB;

  f32x4 accA[8], accB[8];               // [n] x (h0..h0+3, h0+4..h0+7)
#pragma unroll
  for (int n = 0; n < 8; ++n) { accA[n] = (f32x4)0.f; accB[n] = (f32x4)0.f; }

  // stage chunk cc (8 uu) into buffer sel: 16 w1-calls + 1 ut-call per wave
#define STAGE(CC, SEL)                                                        \
  {                                                                           \
    float* wb = smem + (SEL)*16384;                                           \
    float* ub = smem + 32768 + (SEL)*1024;                                    \
    const float* wsrc = w1slab + (size_t)(CC)*8 * 8192;                       \
    const float* usrc = utslab + (size_t)(CC)*8 * 512;                        \
    _Pragma("unroll")                                                         \
    for (int i = 0; i < 16; ++i) {                                            \
      int s = w * 1024 + i * 64 + L;   /* 16-B slot: uul = s>>9, rem s&511 */ \
      GLOAD_LDS(wsrc + (size_t)(s >> 9) * 8192 + (size_t)(s & 511) * 4,       \
                wb + (size_t)(w * 1024 + i * 64) * 4);                        \
    }                                                                         \
    {                                                                         \
      int s2 = w * 64 + L;             /* 16-B slot: uul = s2>>5 */           \
      GLOAD_LDS(usrc + (size_t)(s2 >> 5) * 512 + (size_t)(s2 & 31) * 4,       \
                ub + (size_t)(w * 64) * 4);                                   \
    }                                                                         \
  }

  STAGE(0, 0)
  __syncthreads();                      // vmcnt(0)+barrier: chunk 0 ready
  int sel = 0;
  for (int cc = 0; cc < 8; ++cc) {
    if (cc < 7) STAGE(cc + 1, sel ^ 1)  // loads fly during compute below
    const float* wb = smem + sel * 16384;
    const float* ub = smem + 32768 + sel * 1024;
#pragma unroll
    for (int uul = 0; uul < 8; ++uul) {
      f32x4 w0  = *(const f32x4*)(wb + uul * 2048 + vl * 128 + h0);
      f32x4 w1v = *(const f32x4*)(wb + uul * 2048 + vl * 128 + h0 + 4);
      f32x4 u0  = *(const f32x4*)(ub + uul * 128 + vl * 8);
      f32x4 u1  = *(const f32x4*)(ub + uul * 128 + vl * 8 + 4);
      accA[0] += w0 * u0.x; accB[0] += w1v * u0.x;
      accA[1] += w0 * u0.y; accB[1] += w1v * u0.y;
      accA[2] += w0 * u0.z; accB[2] += w1v * u0.z;
      accA[3] += w0 * u0.w; accB[3] += w1v * u0.w;
      accA[4] += w0 * u1.x; accB[4] += w1v * u1.x;
      accA[5] += w0 * u1.y; accB[5] += w1v * u1.y;
      accA[6] += w0 * u1.z; accB[6] += w1v * u1.z;
      accA[7] += w0 * u1.w; accB[7] += w1v * u1.w;
    }
    __syncthreads();                    // drain vmcnt(0): next chunk landed;
    sel ^= 1;                           // all waves done reading this buf
  }
#undef STAGE

  // ---- epilogue: LDS transpose (aliases staging smem; all compute sync'd) ----
  float* tile = smem;                   // [n][h][v_local], row stride 17
#pragma unroll
  for (int n = 0; n < 8; ++n)
#pragma unroll
    for (int j = 0; j < 4; ++j) {
      tile[((n << 7) + h0 + j) * 17 + vl] = accA[n][j];
      tile[((n << 7) + h0 + 4 + j) * 17 + vl] = accB[n][j];
    }
  __syncthreads();

  // ---- bf16 store: 4096 u16x4 units (n(8), h(128), c4(4)), 16/thread ----
#pragma unroll
  for (int k = 0; k < 16; ++k) {
    int flat = k * 256 + t;
    int c4 = flat & 3, h = (flat >> 2) & 127, n = flat >> 9;
    const float* src = &tile[((n << 7) + h) * 17 + c4 * 4];
    u16x4 o;
#pragma unroll
    for (int j = 0; j < 4; ++j) {
      __hip_bfloat16 hv = __float2bfloat16(src[j]);
      o[j] = *(u16*)&hv;
    }
    *(u16x4*)(at + (((size_t)n * RD + rr) * HD + h) * VD + vq * 16 + c4 * 4) = o;
  }
}

// ---------------- k_main: fused GEMM1 (P^T = A_r^T * V^T) + relu*r + GEMM2 ------
// R6 known-good structure (512 blocks x 256 thr, 64 KB double-buffered swizzled
// Plds, ONE lds_barrier per rr).  Unchanged.
__global__ __launch_bounds__(256, 1) void k_main(const float* __restrict__ vin,
                                                 const u16* __restrict__ at,
                                                 const u16* __restrict__ w2t,
                                                 const float* __restrict__ rt,
                                                 float* __restrict__ pbuf) {
  __shared__ __align__(16) char Plds[2 * 128 * 256];   // 64 KB exactly
  int b = blockIdx.x;                 // 512 = n(8) x stile(8) x rchunk(8)
  int rc = b & 7, st = (b >> 3) & 7, n = b >> 6;
  int t = threadIdx.x;
  int w = t >> 6, L = t & 63, q = L >> 4, c = L & 15;
  int g2m = w >> 1, g2x = w & 1;      // GEMM2: s-half x x-half

  // V fragments (B-operand of GEMM1), register-resident for all r-steps
  bf16x8 vf[4][2];
#pragma unroll
  for (int nt = 0; nt < 4; ++nt)
#pragma unroll
    for (int ks = 0; ks < 2; ++ks) {
      int s = (w & 1) * 64 + nt * 16 + c;
      const float* vp = vin + ((size_t)(n * SITES + st * 128 + s) * VD + ks * 32 + q * 8);
      f32x4 a0 = *(const f32x4*)vp;
      f32x4 a1 = *(const f32x4*)(vp + 4);
      bf16x8 f;
      f[0] = (__bf16)a0.x; f[1] = (__bf16)a0.y; f[2] = (__bf16)a0.z; f[3] = (__bf16)a0.w;
      f[4] = (__bf16)a1.x; f[5] = (__bf16)a1.y; f[6] = (__bf16)a1.z; f[7] = (__bf16)a1.w;
      vf[nt][ks] = f;
    }

  f32x4 o[4][2];
#pragma unroll
  for (int i = 0; i < 4; i++)
#pragma unroll
    for (int j = 0; j < 2; j++) o[i][j] = (f32x4)0.f;

  int g1m = w >> 1, g1n = w & 1;      // GEMM1: h-half x s-half
  for (int rr = rc * 8; rr < rc * 8 + 8; ++rr) {
    const u16* abase = at + (size_t)(n * RD + rr) * 8192;   // [h][v] plain

    // A-frags direct from global: 16B = 8 consecutive v at fixed h
    bf16x8 af[4][2];
#pragma unroll
    for (int mt = 0; mt < 4; ++mt)
#pragma unroll
      for (int ks = 0; ks < 2; ++ks) {
        int h = g1m * 64 + mt * 16 + c;
        int vb = ks * 4 + q;
        af[mt][ks] = *(const bf16x8*)(abase + (size_t)h * VD + vb * 8);
      }
    // W2r b-frags from global (L2-hot)
    u32x4 wraw[2][4];
#pragma unroll
    for (int xt = 0; xt < 2; ++xt)
#pragma unroll
      for (int k2 = 0; k2 < 4; ++k2) {
        int xg = g2x * 32 + xt * 16 + c;
        wraw[xt][k2] = *(const u32x4*)((const char*)w2t +
                        (((size_t)(rr * XD + xg)) * HD + k2 * 32 + q * 8) * 2);
      }
    float rsc[4];
#pragma unroll
    for (int nt = 0; nt < 4; ++nt)
      rsc[nt] = rt[(size_t)(n * RD + rr) * SITES + st * 128 + g1n * 64 + nt * 16 + c];

    // GEMM1: D = A_r^T (m=h) x V^T (n=s), K=v=64
    f32x4 cc[4][4];
#pragma unroll
    for (int mt = 0; mt < 4; ++mt)
#pragma unroll
      for (int nt = 0; nt < 4; ++nt) cc[mt][nt] = (f32x4)0.f;
#pragma unroll
    for (int ks = 0; ks < 2; ++ks)
#pragma unroll
      for (int mt = 0; mt < 4; ++mt)
#pragma unroll
        for (int nt = 0; nt < 4; ++nt)
          cc[mt][nt] = __builtin_amdgcn_mfma_f32_16x16x32_bf16(af[mt][ks], vf[nt][ks],
                                                               cc[mt][nt], 0, 0, 0);

    // relu, scale by r, pack to Plds buf rr&1, XOR-swizzled 16B blocks:
    // element (s, h-block hb8=h>>3) stored at block (hb8 ^ (s&15)) within row s.
    char* PB = Plds + (rr & 1) * 32768;
#pragma unroll
    for (int mt = 0; mt < 4; ++mt)
#pragma unroll
      for (int nt = 0; nt < 4; ++nt) {
        float sc = rsc[nt];
        bf16x4 pv;
#pragma unroll
        for (int jj = 0; jj < 4; ++jj) {
          float x = cc[mt][nt][jj];
          x = x > 0.f ? x : 0.f;
          pv[jj] = (__bf16)(x * sc);
        }
        int s = g1n * 64 + nt * 16 + c;          // s&15 == c
        int blk = g1m * 8 + mt * 2 + (q >> 1);   // = h>>3
        *(bf16x4*)(PB + (size_t)s * 256 + (size_t)((blk ^ c) * 16 + (q & 1) * 8)) = pv;
      }
    lds_barrier();   // lgkm-only barrier — no vmcnt(0) drain per rr

    // GEMM2: O[s,x] += P (m=s, A-op) x W2r^T (n=x), K=h=128
#pragma unroll
    for (int k2 = 0; k2 < 4; ++k2) {
      bf16x8 wf0 = __builtin_bit_cast(bf16x8, wraw[0][k2]);
      bf16x8 wf1 = __builtin_bit_cast(bf16x8, wraw[1][k2]);
#pragma unroll
      for (int mt = 0; mt < 4; ++mt) {
        int s = g2m * 64 + mt * 16 + c;          // s&15 == c
        int blk = k2 * 4 + q;                    // = h>>3
        bf16x8 pf = *(const bf16x8*)(PB + (size_t)s * 256 + (size_t)((blk ^ c) * 16));
        o[mt][0] = __builtin_amdgcn_mfma_f32_16x16x32_bf16(pf, wf0, o[mt][0], 0, 0, 0);
        o[mt][1] = __builtin_amdgcn_mfma_f32_16x16x32_bf16(pf, wf1, o[mt][1], 0, 0, 0);
      }
    }
  }
  // epilogue: plain vector stores to partial buffer pbuf[rc][n][st][x][s]
#pragma unroll
  for (int mt = 0; mt < 4; ++mt)
#pragma unroll
    for (int xt = 0; xt < 2; ++xt) {
      int s0 = g2m * 64 + mt * 16 + q * 4;
      int x = g2x * 32 + xt * 16 + c;
      size_t off = ((((size_t)rc * NB + n) * 8 + st) * XD + x) * 128 + s0;
      *(f32x4*)(pbuf + off) = o[mt][xt];
    }
}

// ---------------- k_reduce: out[n][s][x] = sum_rc pbuf[rc][n][st][x][s] ---------
__global__ __launch_bounds__(256) void k_reduce(const float* __restrict__ pbuf,
                                                float* __restrict__ out) {
  __shared__ float tile[128][17];
  int b = blockIdx.x;                 // 256 = n(8) x st(8) x xq(4)
  int n = b >> 5, st = (b >> 2) & 7, xq = b & 3;
  int t = threadIdx.x;
  int sq = t & 31, xl = t >> 5;       // phase-1: s-quad, x-lane (8)
#pragma unroll
  for (int p = 0; p < 2; ++p) {
    int x = xq * 16 + p * 8 + xl;
    f32x4 sum = (f32x4)0.f;
#pragma unroll
    for (int rcc = 0; rcc < 8; ++rcc) {
      size_t off = ((((size_t)rcc * NB + n) * 8 + st) * XD + x) * 128 + sq * 4;
      f32x4 d = *(const f32x4*)(pbuf + off);
      sum.x += d.x; sum.y += d.y; sum.z += d.z; sum.w += d.w;
    }
#pragma unroll
    for (int k = 0; k < 4; ++k) tile[sq * 4 + k][p * 8 + xl] = sum[k];
  }
  __syncthreads();
  // phase-2: coalesced out write, f32x4 along x
#pragma unroll
  for (int k = 0; k < 2; ++k) {
    int flat = k * 256 + t;
    int s = flat >> 2, c4 = flat & 3;
    f32x4 o;
#pragma unroll
    for (int j = 0; j < 4; ++j) o[j] = tile[s][c4 * 4 + j];
    *(f32x4*)(out + ((size_t)(n * SITES + st * 128 + s) * XD + xq * 16 + c4 * 4)) = o;
  }
}

extern "C" void kernel_launch(void* const* d_in, const int* in_sizes, int n_in,
                              void* d_out, int out_size, void* d_ws, size_t ws_size,
                              hipStream_t stream) {
  const float* r  = (const float*)d_in[0];
  const float* u  = (const float*)d_in[1];
  const float* v  = (const float*)d_in[2];
  const float* w1 = (const float*)d_in[3];
  const float* w2 = (const float*)d_in[4];
  float* out = (float*)d_out;
  char* ws = (char*)d_ws;
  u16* at     = (u16*)(ws);                         // 8 MB  bf16 a, [n][r][h][v]
  u16* w2t    = (u16*)(ws + ((size_t)8 << 20));     // 1 MB  bf16 w2 [r][x][h]
  float* rt   = (float*)(ws + ((size_t)9 << 20));   // 2 MB  fp32 r [n][r][s]
  float* ut   = (float*)(ws + ((size_t)11 << 20));  // 8 MB  fp32 u [r][u][v][n]
  float* pbuf = (float*)(ws + ((size_t)19 << 20));  // 16 MB fp32 out-partials [rc][n][st][x][s]

  hipLaunchKernelGGL(kprep, dim3(2432), dim3(256), 0, stream, w2, w2t, r, rt, u, ut);
  hipLaunchKernelGGL(k_a_full, dim3(256), dim3(256), 0, stream, w1, ut, at);
  hipLaunchKernelGGL(k_main, dim3(512), dim3(256), 0, stream, v, at, w2t, rt, pbuf);
  hipLaunchKernelGGL(k_reduce, dim3(256), dim3(256), 0, stream, pbuf, out);
}

// Round 7
// 260.967 us; speedup vs baseline: 1.0029x; 1.0029x over previous
//
#include <hip/hip_runtime.h>
#include <hip/hip_bf16.h>

#define RD 64
#define UD 64
#define VD 64
#define HD 128
#define XD 64
#define NB 8
#define SITES 1024

typedef float f32x4 __attribute__((ext_vector_type(4)));
typedef float f32x2 __attribute__((ext_vector_type(2)));
typedef __bf16 bf16x4 __attribute__((ext_vector_type(4)));
typedef __bf16 bf16x8 __attribute__((ext_vector_type(8)));
typedef unsigned int u32x4 __attribute__((ext_vector_type(4)));
typedef unsigned short u16;
typedef unsigned short u16x4 __attribute__((ext_vector_type(4)));

// Raw workgroup barrier WITHOUT the vmcnt(0) drain __syncthreads carries.
// 0xC07F = lgkmcnt(0), vmcnt=63 (open), expcnt=7 (open) on gfx9-lineage.
__device__ __forceinline__ void lds_barrier() {
  __builtin_amdgcn_s_waitcnt(0xC07F);
  __builtin_amdgcn_s_barrier();
}

// ---------------- kprep: w2 and r transforms only (u-pass removed in R7) --------
// b < 256   : w2 [x][r][h] fp32 -> w2t bf16 [r][x][h]
// else      : r  [n][s][r] fp32 -> rt fp32 [n][r][s]   (128 blocks)
__global__ void kprep(const float* __restrict__ w2, u16* __restrict__ w2t,
                      const float* __restrict__ r, float* __restrict__ rt) {
  __shared__ float tl[64][68];
  int b = blockIdx.x;
  int t = threadIdx.x;
  if (b < 256) {
    int rr = b >> 2, qq = b & 3;
    for (int i = 0; i < 8; ++i) {
      int idx = qq * 2048 + i * 256 + t;   // (x,h)
      int x = idx >> 7, h = idx & 127;
      float val = w2[((size_t)x * RD + rr) * HD + h];
      __hip_bfloat16 hv = __float2bfloat16(val);
      w2t[((size_t)rr * XD + x) * HD + h] = *(u16*)&hv;
    }
  } else {
    int bb = b - 256;
    int n = bb >> 4, sb = (bb & 15) * 64;
    for (int i = 0; i < 4; ++i) {
      int flat = i * 256 + t;
      int s = flat >> 4, ch = flat & 15;
      f32x4 d = *(const f32x4*)(r + ((size_t)(n * SITES + sb + s) * RD + ch * 4));
      *(f32x4*)&tl[s][ch * 4] = d;
    }
    __syncthreads();
    for (int i = 0; i < 4; ++i) {
      int flat = i * 256 + t;
      int rr = flat >> 4, ch = flat & 15;
      f32x4 o;
      o.x = tl[ch * 4 + 0][rr];
      o.y = tl[ch * 4 + 1][rr];
      o.z = tl[ch * 4 + 2][rr];
      o.w = tl[ch * 4 + 3][rr];
      *(f32x4*)(rt + ((size_t)(n * RD + rr) * SITES + sb + ch * 4)) = o;
    }
  }
}

// ---------------- k_a_full v7: R3's v3 structure + in-block u staging -----------
// R6 post-mortem: five k_a_full structures all pin at 2.8-2.9 TB/s -> that is
// ~92% of the platform READ-stream ceiling (copy ubench 6.29 TB/s counted R+W
// => ~3.1 TB/s per direction; fills do 6.6-6.9 TB/s pure writes).  The w1
// stream is accepted as structural; v7 reverts to the best variant (v3,
// 512 blocks x 512 thr, u-split ring, 16 waves/CU) and instead removes the ut
// round-trip: each block stages its self-contained 64-KB u-slab (raw [n][uu][vl]
// layout, conflict-free f32x4 copy, no transpose) and the FMA loop reads u as
// 8 broadcast scalar ds_reads per uu (addr = n*2048 + uug*32 + vl: 8 distinct
// banks, 8 lanes/addr broadcast -> conflict-free).  kprep's 2048-block u-pass
// is deleted.  uslab (64 KB) aliases red+tile (65 KB) -> one extra barrier
// after the FMA loop before red is written.  Accumulation order (half0+half1,
// uu ascending) unchanged -> bit-identical at vs R3.
#define PF 4
__global__ __launch_bounds__(512, 4) void k_a_full(const float* __restrict__ w1,
                                                   const float* __restrict__ u,
                                                   u16* __restrict__ at) {
  // phase 1: uslab[0..16384) = [n(8)][uu(64)][vl(32)]
  // phase 2 (after barrier): red[0..8192), tile[8192..16640)
  __shared__ __align__(16) float smem[16640];   // 65 KB
  int b = blockIdx.x;                   // 512 = rr(64) x vh(2) x hb(4)
  int rr = b >> 3, vh = (b >> 2) & 1, hb = b & 3;
  int t = threadIdx.x;
  int uh = t >> 8;                      // u-half: uu in [uh*32, uh*32+32)
  int L = t & 255;
  int vl = L >> 3, hs = L & 7;          // v-local (32), h-strip (8 strips x 4 h)
  int v = vh * 32 + vl;
  int h0 = hb * 32 + hs * 4;

  // ---- stage u-slab: u[n][rr][uu][vh*32+vg*4 ..+4] -> smem[s*4] --------------
  {
    const float* ub = u + (size_t)rr * UD * VD + (size_t)vh * 32;
#pragma unroll
    for (int i = 0; i < 8; ++i) {
      int s = i * 512 + t;              // n = s>>9, uu = (s>>3)&63, vg = s&7
      int n = s >> 9, uu = (s >> 3) & 63, vg = s & 7;
      f32x4 d = *(const f32x4*)(ub + (size_t)n * (RD * UD * VD) + (size_t)uu * VD + vg * 4);
      *(f32x4*)&smem[s * 4] = d;
    }
  }
  __syncthreads();

  const float* w1p = w1 + (((size_t)(rr * UD + uh * 32)) * VD + v) * HD + h0;
  const size_t wstep = (size_t)VD * HD;   // floats per uu in w1
  const float* uslab = smem + (size_t)uh * 32 * 32 + vl;  // + n*2048 + uul*32

  f32x4 acc[8];
#pragma unroll
  for (int n = 0; n < 8; ++n) acc[n] = (f32x4)0.f;

  // PF=4 w1 prefetch ring, fully-unrolled loop -> static indices
  f32x4 wa[PF];
#pragma unroll
  for (int p = 0; p < PF; ++p) wa[p] = *(const f32x4*)(w1p + (size_t)p * wstep);
#pragma unroll
  for (int uul = 0; uul < 32; ++uul) {
    const int p = uul & (PF - 1);
    f32x4 wv = wa[p];
    if (uul + PF < 32) wa[p] = *(const f32x4*)(w1p + (size_t)(uul + PF) * wstep);
    const float* up = uslab + (size_t)uul * 32;
    acc[0] += wv * up[0 * 2048];
    acc[1] += wv * up[1 * 2048];
    acc[2] += wv * up[2 * 2048];
    acc[3] += wv * up[3 * 2048];
    acc[4] += wv * up[4 * 2048];
    acc[5] += wv * up[5 * 2048];
    acc[6] += wv * up[6 * 2048];
    acc[7] += wv * up[7 * 2048];
  }

  __syncthreads();                      // all waves done with uslab (red aliases it)

  // ---- reduce the two u-halves: uh=1 stages to red, uh=0 adds ----
  float* red  = smem;                   // 8192 f (32 KB)
  float* tile = smem + 8192;            // 8448 f (33 KB)
  if (uh == 1) {
#pragma unroll
    for (int n = 0; n < 8; ++n)
      *(f32x4*)&red[L * 32 + ((n ^ (L & 7)) << 2)] = acc[n];
  }
  __syncthreads();
  if (uh == 0) {
#pragma unroll
    for (int n = 0; n < 8; ++n)
      acc[n] += *(const f32x4*)&red[L * 32 + ((n ^ (L & 7)) << 2)];
    // transposed scatter into tile[n][h_local][v_local] (stride 33 breaks banks)
#pragma unroll
    for (int n = 0; n < 8; ++n)
#pragma unroll
      for (int j = 0; j < 4; ++j)
        tile[(n * 32 + hs * 4 + j) * 33 + vl] = acc[n][j];
  }
  __syncthreads();

  // ---- coalesced bf16 store: 2048 u16x4 units, 4 per thread ----
#pragma unroll
  for (int k = 0; k < 4; ++k) {
    int flat = k * 512 + t;
    int vs = flat & 7, hl = (flat >> 3) & 31, n = flat >> 8;
    f32x4 blk = *(const f32x4*)&tile[(n * 32 + hl) * 33 + vs * 4];
    u16x4 o;
#pragma unroll
    for (int j = 0; j < 4; ++j) {
      __hip_bfloat16 hv = __float2bfloat16(blk[j]);
      o[j] = *(u16*)&hv;
    }
    *(u16x4*)(at + ((size_t)(n * RD + rr) * HD + hb * 32 + hl) * VD + vh * 32 + vs * 4) = o;
  }
}

// ---------------- k_main: fused GEMM1 (P^T = A_r^T * V^T) + relu*r + GEMM2 ------
// R6 known-good structure (512 blocks x 256 thr, 64 KB double-buffered swizzled
// Plds, ONE lds_barrier per rr).  Unchanged.
__global__ __launch_bounds__(256, 1) void k_main(const float* __restrict__ vin,
                                                 const u16* __restrict__ at,
                                                 const u16* __restrict__ w2t,
                                                 const float* __restrict__ rt,
                                                 float* __restrict__ pbuf) {
  __shared__ __align__(16) char Plds[2 * 128 * 256];   // 64 KB exactly
  int b = blockIdx.x;                 // 512 = n(8) x stile(8) x rchunk(8)
  int rc = b & 7, st = (b >> 3) & 7, n = b >> 6;
  int t = threadIdx.x;
  int w = t >> 6, L = t & 63, q = L >> 4, c = L & 15;
  int g2m = w >> 1, g2x = w & 1;      // GEMM2: s-half x x-half

  // V fragments (B-operand of GEMM1), register-resident for all r-steps
  bf16x8 vf[4][2];
#pragma unroll
  for (int nt = 0; nt < 4; ++nt)
#pragma unroll
    for (int ks = 0; ks < 2; ++ks) {
      int s = (w & 1) * 64 + nt * 16 + c;
      const float* vp = vin + ((size_t)(n * SITES + st * 128 + s) * VD + ks * 32 + q * 8);
      f32x4 a0 = *(const f32x4*)vp;
      f32x4 a1 = *(const f32x4*)(vp + 4);
      bf16x8 f;
      f[0] = (__bf16)a0.x; f[1] = (__bf16)a0.y; f[2] = (__bf16)a0.z; f[3] = (__bf16)a0.w;
      f[4] = (__bf16)a1.x; f[5] = (__bf16)a1.y; f[6] = (__bf16)a1.z; f[7] = (__bf16)a1.w;
      vf[nt][ks] = f;
    }

  f32x4 o[4][2];
#pragma unroll
  for (int i = 0; i < 4; i++)
#pragma unroll
    for (int j = 0; j < 2; j++) o[i][j] = (f32x4)0.f;

  int g1m = w >> 1, g1n = w & 1;      // GEMM1: h-half x s-half
  for (int rr = rc * 8; rr < rc * 8 + 8; ++rr) {
    const u16* abase = at + (size_t)(n * RD + rr) * 8192;   // [h][v] plain

    // A-frags direct from global: 16B = 8 consecutive v at fixed h
    bf16x8 af[4][2];
#pragma unroll
    for (int mt = 0; mt < 4; ++mt)
#pragma unroll
      for (int ks = 0; ks < 2; ++ks) {
        int h = g1m * 64 + mt * 16 + c;
        int vb = ks * 4 + q;
        af[mt][ks] = *(const bf16x8*)(abase + (size_t)h * VD + vb * 8);
      }
    // W2r b-frags from global (L2-hot)
    u32x4 wraw[2][4];
#pragma unroll
    for (int xt = 0; xt < 2; ++xt)
#pragma unroll
      for (int k2 = 0; k2 < 4; ++k2) {
        int xg = g2x * 32 + xt * 16 + c;
        wraw[xt][k2] = *(const u32x4*)((const char*)w2t +
                        (((size_t)(rr * XD + xg)) * HD + k2 * 32 + q * 8) * 2);
      }
    float rsc[4];
#pragma unroll
    for (int nt = 0; nt < 4; ++nt)
      rsc[nt] = rt[(size_t)(n * RD + rr) * SITES + st * 128 + g1n * 64 + nt * 16 + c];

    // GEMM1: D = A_r^T (m=h) x V^T (n=s), K=v=64
    f32x4 cc[4][4];
#pragma unroll
    for (int mt = 0; mt < 4; ++mt)
#pragma unroll
      for (int nt = 0; nt < 4; ++nt) cc[mt][nt] = (f32x4)0.f;
#pragma unroll
    for (int ks = 0; ks < 2; ++ks)
#pragma unroll
      for (int mt = 0; mt < 4; ++mt)
#pragma unroll
        for (int nt = 0; nt < 4; ++nt)
          cc[mt][nt] = __builtin_amdgcn_mfma_f32_16x16x32_bf16(af[mt][ks], vf[nt][ks],
                                                               cc[mt][nt], 0, 0, 0);

    // relu, scale by r, pack to Plds buf rr&1, XOR-swizzled 16B blocks:
    // element (s, h-block hb8=h>>3) stored at block (hb8 ^ (s&15)) within row s.
    char* PB = Plds + (rr & 1) * 32768;
#pragma unroll
    for (int mt = 0; mt < 4; ++mt)
#pragma unroll
      for (int nt = 0; nt < 4; ++nt) {
        float sc = rsc[nt];
        bf16x4 pv;
#pragma unroll
        for (int jj = 0; jj < 4; ++jj) {
          float x = cc[mt][nt][jj];
          x = x > 0.f ? x : 0.f;
          pv[jj] = (__bf16)(x * sc);
        }
        int s = g1n * 64 + nt * 16 + c;          // s&15 == c
        int blk = g1m * 8 + mt * 2 + (q >> 1);   // = h>>3
        *(bf16x4*)(PB + (size_t)s * 256 + (size_t)((blk ^ c) * 16 + (q & 1) * 8)) = pv;
      }
    lds_barrier();   // lgkm-only barrier — no vmcnt(0) drain per rr

    // GEMM2: O[s,x] += P (m=s, A-op) x W2r^T (n=x), K=h=128
#pragma unroll
    for (int k2 = 0; k2 < 4; ++k2) {
      bf16x8 wf0 = __builtin_bit_cast(bf16x8, wraw[0][k2]);
      bf16x8 wf1 = __builtin_bit_cast(bf16x8, wraw[1][k2]);
#pragma unroll
      for (int mt = 0; mt < 4; ++mt) {
        int s = g2m * 64 + mt * 16 + c;          // s&15 == c
        int blk = k2 * 4 + q;                    // = h>>3
        bf16x8 pf = *(const bf16x8*)(PB + (size_t)s * 256 + (size_t)((blk ^ c) * 16));
        o[mt][0] = __builtin_amdgcn_mfma_f32_16x16x32_bf16(pf, wf0, o[mt][0], 0, 0, 0);
        o[mt][1] = __builtin_amdgcn_mfma_f32_16x16x32_bf16(pf, wf1, o[mt][1], 0, 0, 0);
      }
    }
  }
  // epilogue: plain vector stores to partial buffer pbuf[rc][n][st][x][s]
#pragma unroll
  for (int mt = 0; mt < 4; ++mt)
#pragma unroll
    for (int xt = 0; xt < 2; ++xt) {
      int s0 = g2m * 64 + mt * 16 + q * 4;
      int x = g2x * 32 + xt * 16 + c;
      size_t off = ((((size_t)rc * NB + n) * 8 + st) * XD + x) * 128 + s0;
      *(f32x4*)(pbuf + off) = o[mt][xt];
    }
}

// ---------------- k_reduce: out[n][s][x] = sum_rc pbuf[rc][n][st][x][s] ---------
__global__ __launch_bounds__(256) void k_reduce(const float* __restrict__ pbuf,
                                                float* __restrict__ out) {
  __shared__ float tile[128][17];
  int b = blockIdx.x;                 // 256 = n(8) x st(8) x xq(4)
  int n = b >> 5, st = (b >> 2) & 7, xq = b & 3;
  int t = threadIdx.x;
  int sq = t & 31, xl = t >> 5;       // phase-1: s-quad, x-lane (8)
#pragma unroll
  for (int p = 0; p < 2; ++p) {
    int x = xq * 16 + p * 8 + xl;
    f32x4 sum = (f32x4)0.f;
#pragma unroll
    for (int rcc = 0; rcc < 8; ++rcc) {
      size_t off = ((((size_t)rcc * NB + n) * 8 + st) * XD + x) * 128 + sq * 4;
      f32x4 d = *(const f32x4*)(pbuf + off);
      sum.x += d.x; sum.y += d.y; sum.z += d.z; sum.w += d.w;
    }
#pragma unroll
    for (int k = 0; k < 4; ++k) tile[sq * 4 + k][p * 8 + xl] = sum[k];
  }
  __syncthreads();
  // phase-2: coalesced out write, f32x4 along x
#pragma unroll
  for (int k = 0; k < 2; ++k) {
    int flat = k * 256 + t;
    int s = flat >> 2, c4 = flat & 3;
    f32x4 o;
#pragma unroll
    for (int j = 0; j < 4; ++j) o[j] = tile[s][c4 * 4 + j];
    *(f32x4*)(out + ((size_t)(n * SITES + st * 128 + s) * XD + xq * 16 + c4 * 4)) = o;
  }
}

extern "C" void kernel_launch(void* const* d_in, const int* in_sizes, int n_in,
                              void* d_out, int out_size, void* d_ws, size_t ws_size,
                              hipStream_t stream) {
  const float* r  = (const float*)d_in[0];
  const float* u  = (const float*)d_in[1];
  const float* v  = (const float*)d_in[2];
  const float* w1 = (const float*)d_in[3];
  const float* w2 = (const float*)d_in[4];
  float* out = (float*)d_out;
  char* ws = (char*)d_ws;
  u16* at     = (u16*)(ws);                         // 8 MB  bf16 a, [n][r][h][v]
  u16* w2t    = (u16*)(ws + ((size_t)8 << 20));     // 1 MB  bf16 w2 [r][x][h]
  float* rt   = (float*)(ws + ((size_t)9 << 20));   // 2 MB  fp32 r [n][r][s]
  float* pbuf = (float*)(ws + ((size_t)19 << 20));  // 16 MB fp32 out-partials [rc][n][st][x][s]

  hipLaunchKernelGGL(kprep, dim3(384), dim3(256), 0, stream, w2, w2t, r, rt);
  hipLaunchKernelGGL(k_a_full, dim3(512), dim3(512), 0, stream, w1, u, at);
  hipLaunchKernelGGL(k_main, dim3(512), dim3(256), 0, stream, v, at, w2t, rt, pbuf);
  hipLaunchKernelGGL(k_reduce, dim3(256), dim3(256), 0, stream, pbuf, out);
}

// Round 8
// 257.332 us; speedup vs baseline: 1.0171x; 1.0141x over previous
//
#include <hip/hip_runtime.h>
#include <hip/hip_bf16.h>

#define RD 64
#define UD 64
#define VD 64
#define HD 128
#define XD 64
#define NB 8
#define SITES 1024

typedef float f32x4 __attribute__((ext_vector_type(4)));
typedef float f32x2 __attribute__((ext_vector_type(2)));
typedef __bf16 bf16x4 __attribute__((ext_vector_type(4)));
typedef __bf16 bf16x8 __attribute__((ext_vector_type(8)));
typedef unsigned int u32x4 __attribute__((ext_vector_type(4)));
typedef unsigned short u16;
typedef unsigned short u16x4 __attribute__((ext_vector_type(4)));

// Raw workgroup barrier WITHOUT the vmcnt(0) drain __syncthreads carries.
// 0xC07F = lgkmcnt(0), vmcnt=63 (open), expcnt=7 (open) on gfx9-lineage.
__device__ __forceinline__ void lds_barrier() {
  __builtin_amdgcn_s_waitcnt(0xC07F);
  __builtin_amdgcn_s_barrier();
}

// ---------------- k_a_full v8: v7 + XCD-bijective swizzle + fused kprep ---------
// R7 post-mortem: the 8 (vh,hb)-sibling blocks of one rr share a 128-KB u-slab,
// but consecutive blockIdx round-robins XCDs -> siblings on 8 DIFFERENT XCDs,
// private L2s can't share -> u fetched ~8x (+~25 MB at the ~2.9 TB/s read cap
// ~= +10 us).  v8's swizzle l = (p&7)*64 + (p>>3) (bijective: 512 = 8*64) puts
// all 8 siblings at p, p+8, ..., p+56 -> same p%8 -> same XCD; slab L2-resident
// -> u fetched ~once per rr.  w1 then partitions per-XCD into contiguous
// 16.8-MB ranges.  kprep (w2->w2t bf16, r->rt transpose) is folded in as
// blocks 512..895 (512-thread re-indexing, tl overlaid on smem) -> one less
// launch.  Per-block computation identical to R7 -> bit-identical at.
#define PF 4
__global__ __launch_bounds__(512, 4) void k_a_full(const float* __restrict__ w1,
                                                   const float* __restrict__ u,
                                                   u16* __restrict__ at,
                                                   const float* __restrict__ w2,
                                                   u16* __restrict__ w2t,
                                                   const float* __restrict__ r,
                                                   float* __restrict__ rt) {
  // a-blocks: phase 1 uslab[0..16384) = [n(8)][uu(64)][vl(32)]
  //           phase 2 (after barrier): red[0..8192), tile[8192..16640)
  // kprep-blocks: tl[64][68] overlay (4352 floats)
  __shared__ __align__(16) float smem[16640];   // 65 KB
  int p = blockIdx.x;
  int t = threadIdx.x;

  if (p >= 512) {                       // ---------- fused kprep ----------
    int bb = p - 512;
    if (bb < 256) {                     // w2 [x][r][h] fp32 -> w2t bf16 [r][x][h]
      int rr = bb >> 2, qq = bb & 3;
#pragma unroll
      for (int i = 0; i < 4; ++i) {
        int idx = qq * 2048 + i * 512 + t;   // (x,h)
        int x = idx >> 7, h = idx & 127;
        float val = w2[((size_t)x * RD + rr) * HD + h];
        __hip_bfloat16 hv = __float2bfloat16(val);
        w2t[((size_t)rr * XD + x) * HD + h] = *(u16*)&hv;
      }
    } else {                            // r [n][s][r] fp32 -> rt fp32 [n][r][s]
      float (*tl)[68] = (float(*)[68])smem;
      int bb2 = bb - 256;
      int n = bb2 >> 4, sb = (bb2 & 15) * 64;
#pragma unroll
      for (int i = 0; i < 2; ++i) {
        int flat = i * 512 + t;
        int s = flat >> 4, ch = flat & 15;
        f32x4 d = *(const f32x4*)(r + ((size_t)(n * SITES + sb + s) * RD + ch * 4));
        *(f32x4*)&tl[s][ch * 4] = d;
      }
      __syncthreads();
#pragma unroll
      for (int i = 0; i < 2; ++i) {
        int flat = i * 512 + t;
        int rr = flat >> 4, ch = flat & 15;
        f32x4 o;
        o.x = tl[ch * 4 + 0][rr];
        o.y = tl[ch * 4 + 1][rr];
        o.z = tl[ch * 4 + 2][rr];
        o.w = tl[ch * 4 + 3][rr];
        *(f32x4*)(rt + ((size_t)(n * RD + rr) * SITES + sb + ch * 4)) = o;
      }
    }
    return;
  }

  // ---------- a-contraction blocks (swizzled) ----------
  int l = (p & 7) * 64 + (p >> 3);      // bijective on 512; hb/vh sibs same XCD
  int rr = l >> 3, vh = (l >> 2) & 1, hb = l & 3;
  int uh = t >> 8;                      // u-half: uu in [uh*32, uh*32+32)
  int L = t & 255;
  int vl = L >> 3, hs = L & 7;          // v-local (32), h-strip (8 strips x 4 h)
  int v = vh * 32 + vl;
  int h0 = hb * 32 + hs * 4;

  // ---- stage u-slab: u[n][rr][uu][vh*32+vg*4 ..+4] -> smem[s*4] --------------
  {
    const float* ub = u + (size_t)rr * UD * VD + (size_t)vh * 32;
#pragma unroll
    for (int i = 0; i < 8; ++i) {
      int s = i * 512 + t;              // n = s>>9, uu = (s>>3)&63, vg = s&7
      int n = s >> 9, uu = (s >> 3) & 63, vg = s & 7;
      f32x4 d = *(const f32x4*)(ub + (size_t)n * (RD * UD * VD) + (size_t)uu * VD + vg * 4);
      *(f32x4*)&smem[s * 4] = d;
    }
  }
  __syncthreads();

  const float* w1p = w1 + (((size_t)(rr * UD + uh * 32)) * VD + v) * HD + h0;
  const size_t wstep = (size_t)VD * HD;   // floats per uu in w1
  const float* uslab = smem + (size_t)uh * 32 * 32 + vl;  // + n*2048 + uul*32

  f32x4 acc[8];
#pragma unroll
  for (int n = 0; n < 8; ++n) acc[n] = (f32x4)0.f;

  // PF=4 w1 prefetch ring, fully-unrolled loop -> static indices
  f32x4 wa[PF];
#pragma unroll
  for (int pp = 0; pp < PF; ++pp) wa[pp] = *(const f32x4*)(w1p + (size_t)pp * wstep);
#pragma unroll
  for (int uul = 0; uul < 32; ++uul) {
    const int pp = uul & (PF - 1);
    f32x4 wv = wa[pp];
    if (uul + PF < 32) wa[pp] = *(const f32x4*)(w1p + (size_t)(uul + PF) * wstep);
    const float* up = uslab + (size_t)uul * 32;
    acc[0] += wv * up[0 * 2048];
    acc[1] += wv * up[1 * 2048];
    acc[2] += wv * up[2 * 2048];
    acc[3] += wv * up[3 * 2048];
    acc[4] += wv * up[4 * 2048];
    acc[5] += wv * up[5 * 2048];
    acc[6] += wv * up[6 * 2048];
    acc[7] += wv * up[7 * 2048];
  }

  __syncthreads();                      // all waves done with uslab (red aliases it)

  // ---- reduce the two u-halves: uh=1 stages to red, uh=0 adds ----
  float* red  = smem;                   // 8192 f (32 KB)
  float* tile = smem + 8192;            // 8448 f (33 KB)
  if (uh == 1) {
#pragma unroll
    for (int n = 0; n < 8; ++n)
      *(f32x4*)&red[L * 32 + ((n ^ (L & 7)) << 2)] = acc[n];
  }
  __syncthreads();
  if (uh == 0) {
#pragma unroll
    for (int n = 0; n < 8; ++n)
      acc[n] += *(const f32x4*)&red[L * 32 + ((n ^ (L & 7)) << 2)];
    // transposed scatter into tile[n][h_local][v_local] (stride 33 breaks banks)
#pragma unroll
    for (int n = 0; n < 8; ++n)
#pragma unroll
      for (int j = 0; j < 4; ++j)
        tile[(n * 32 + hs * 4 + j) * 33 + vl] = acc[n][j];
  }
  __syncthreads();

  // ---- coalesced bf16 store: 2048 u16x4 units, 4 per thread ----
#pragma unroll
  for (int k = 0; k < 4; ++k) {
    int flat = k * 512 + t;
    int vs = flat & 7, hl = (flat >> 3) & 31, n = flat >> 8;
    f32x4 blk = *(const f32x4*)&tile[(n * 32 + hl) * 33 + vs * 4];
    u16x4 o;
#pragma unroll
    for (int j = 0; j < 4; ++j) {
      __hip_bfloat16 hv = __float2bfloat16(blk[j]);
      o[j] = *(u16*)&hv;
    }
    *(u16x4*)(at + ((size_t)(n * RD + rr) * HD + hb * 32 + hl) * VD + vh * 32 + vs * 4) = o;
  }
}

// ---------------- k_main: fused GEMM1 (P^T = A_r^T * V^T) + relu*r + GEMM2 ------
// R6 known-good structure (512 blocks x 256 thr, 64 KB double-buffered swizzled
// Plds, ONE lds_barrier per rr).  Unchanged.
__global__ __launch_bounds__(256, 1) void k_main(const float* __restrict__ vin,
                                                 const u16* __restrict__ at,
                                                 const u16* __restrict__ w2t,
                                                 const float* __restrict__ rt,
                                                 float* __restrict__ pbuf) {
  __shared__ __align__(16) char Plds[2 * 128 * 256];   // 64 KB exactly
  int b = blockIdx.x;                 // 512 = n(8) x stile(8) x rchunk(8)
  int rc = b & 7, st = (b >> 3) & 7, n = b >> 6;
  int t = threadIdx.x;
  int w = t >> 6, L = t & 63, q = L >> 4, c = L & 15;
  int g2m = w >> 1, g2x = w & 1;      // GEMM2: s-half x x-half

  // V fragments (B-operand of GEMM1), register-resident for all r-steps
  bf16x8 vf[4][2];
#pragma unroll
  for (int nt = 0; nt < 4; ++nt)
#pragma unroll
    for (int ks = 0; ks < 2; ++ks) {
      int s = (w & 1) * 64 + nt * 16 + c;
      const float* vp = vin + ((size_t)(n * SITES + st * 128 + s) * VD + ks * 32 + q * 8);
      f32x4 a0 = *(const f32x4*)vp;
      f32x4 a1 = *(const f32x4*)(vp + 4);
      bf16x8 f;
      f[0] = (__bf16)a0.x; f[1] = (__bf16)a0.y; f[2] = (__bf16)a0.z; f[3] = (__bf16)a0.w;
      f[4] = (__bf16)a1.x; f[5] = (__bf16)a1.y; f[6] = (__bf16)a1.z; f[7] = (__bf16)a1.w;
      vf[nt][ks] = f;
    }

  f32x4 o[4][2];
#pragma unroll
  for (int i = 0; i < 4; i++)
#pragma unroll
    for (int j = 0; j < 2; j++) o[i][j] = (f32x4)0.f;

  int g1m = w >> 1, g1n = w & 1;      // GEMM1: h-half x s-half
  for (int rr = rc * 8; rr < rc * 8 + 8; ++rr) {
    const u16* abase = at + (size_t)(n * RD + rr) * 8192;   // [h][v] plain

    // A-frags direct from global: 16B = 8 consecutive v at fixed h
    bf16x8 af[4][2];
#pragma unroll
    for (int mt = 0; mt < 4; ++mt)
#pragma unroll
      for (int ks = 0; ks < 2; ++ks) {
        int h = g1m * 64 + mt * 16 + c;
        int vb = ks * 4 + q;
        af[mt][ks] = *(const bf16x8*)(abase + (size_t)h * VD + vb * 8);
      }
    // W2r b-frags from global (L2-hot)
    u32x4 wraw[2][4];
#pragma unroll
    for (int xt = 0; xt < 2; ++xt)
#pragma unroll
      for (int k2 = 0; k2 < 4; ++k2) {
        int xg = g2x * 32 + xt * 16 + c;
        wraw[xt][k2] = *(const u32x4*)((const char*)w2t +
                        (((size_t)(rr * XD + xg)) * HD + k2 * 32 + q * 8) * 2);
      }
    float rsc[4];
#pragma unroll
    for (int nt = 0; nt < 4; ++nt)
      rsc[nt] = rt[(size_t)(n * RD + rr) * SITES + st * 128 + g1n * 64 + nt * 16 + c];

    // GEMM1: D = A_r^T (m=h) x V^T (n=s), K=v=64
    f32x4 cc[4][4];
#pragma unroll
    for (int mt = 0; mt < 4; ++mt)
#pragma unroll
      for (int nt = 0; nt < 4; ++nt) cc[mt][nt] = (f32x4)0.f;
#pragma unroll
    for (int ks = 0; ks < 2; ++ks)
#pragma unroll
      for (int mt = 0; mt < 4; ++mt)
#pragma unroll
        for (int nt = 0; nt < 4; ++nt)
          cc[mt][nt] = __builtin_amdgcn_mfma_f32_16x16x32_bf16(af[mt][ks], vf[nt][ks],
                                                               cc[mt][nt], 0, 0, 0);

    // relu, scale by r, pack to Plds buf rr&1, XOR-swizzled 16B blocks:
    // element (s, h-block hb8=h>>3) stored at block (hb8 ^ (s&15)) within row s.
    char* PB = Plds + (rr & 1) * 32768;
#pragma unroll
    for (int mt = 0; mt < 4; ++mt)
#pragma unroll
      for (int nt = 0; nt < 4; ++nt) {
        float sc = rsc[nt];
        bf16x4 pv;
#pragma unroll
        for (int jj = 0; jj < 4; ++jj) {
          float x = cc[mt][nt][jj];
          x = x > 0.f ? x : 0.f;
          pv[jj] = (__bf16)(x * sc);
        }
        int s = g1n * 64 + nt * 16 + c;          // s&15 == c
        int blk = g1m * 8 + mt * 2 + (q >> 1);   // = h>>3
        *(bf16x4*)(PB + (size_t)s * 256 + (size_t)((blk ^ c) * 16 + (q & 1) * 8)) = pv;
      }
    lds_barrier();   // lgkm-only barrier — no vmcnt(0) drain per rr

    // GEMM2: O[s,x] += P (m=s, A-op) x W2r^T (n=x), K=h=128
#pragma unroll
    for (int k2 = 0; k2 < 4; ++k2) {
      bf16x8 wf0 = __builtin_bit_cast(bf16x8, wraw[0][k2]);
      bf16x8 wf1 = __builtin_bit_cast(bf16x8, wraw[1][k2]);
#pragma unroll
      for (int mt = 0; mt < 4; ++mt) {
        int s = g2m * 64 + mt * 16 + c;          // s&15 == c
        int blk = k2 * 4 + q;                    // = h>>3
        bf16x8 pf = *(const bf16x8*)(PB + (size_t)s * 256 + (size_t)((blk ^ c) * 16));
        o[mt][0] = __builtin_amdgcn_mfma_f32_16x16x32_bf16(pf, wf0, o[mt][0], 0, 0, 0);
        o[mt][1] = __builtin_amdgcn_mfma_f32_16x16x32_bf16(pf, wf1, o[mt][1], 0, 0, 0);
      }
    }
  }
  // epilogue: plain vector stores to partial buffer pbuf[rc][n][st][x][s]
#pragma unroll
  for (int mt = 0; mt < 4; ++mt)
#pragma unroll
    for (int xt = 0; xt < 2; ++xt) {
      int s0 = g2m * 64 + mt * 16 + q * 4;
      int x = g2x * 32 + xt * 16 + c;
      size_t off = ((((size_t)rc * NB + n) * 8 + st) * XD + x) * 128 + s0;
      *(f32x4*)(pbuf + off) = o[mt][xt];
    }
}

// ---------------- k_reduce: out[n][s][x] = sum_rc pbuf[rc][n][st][x][s] ---------
__global__ __launch_bounds__(256) void k_reduce(const float* __restrict__ pbuf,
                                                float* __restrict__ out) {
  __shared__ float tile[128][17];
  int b = blockIdx.x;                 // 256 = n(8) x st(8) x xq(4)
  int n = b >> 5, st = (b >> 2) & 7, xq = b & 3;
  int t = threadIdx.x;
  int sq = t & 31, xl = t >> 5;       // phase-1: s-quad, x-lane (8)
#pragma unroll
  for (int p = 0; p < 2; ++p) {
    int x = xq * 16 + p * 8 + xl;
    f32x4 sum = (f32x4)0.f;
#pragma unroll
    for (int rcc = 0; rcc < 8; ++rcc) {
      size_t off = ((((size_t)rcc * NB + n) * 8 + st) * XD + x) * 128 + sq * 4;
      f32x4 d = *(const f32x4*)(pbuf + off);
      sum.x += d.x; sum.y += d.y; sum.z += d.z; sum.w += d.w;
    }
#pragma unroll
    for (int k = 0; k < 4; ++k) tile[sq * 4 + k][p * 8 + xl] = sum[k];
  }
  __syncthreads();
  // phase-2: coalesced out write, f32x4 along x
#pragma unroll
  for (int k = 0; k < 2; ++k) {
    int flat = k * 256 + t;
    int s = flat >> 2, c4 = flat & 3;
    f32x4 o;
#pragma unroll
    for (int j = 0; j < 4; ++j) o[j] = tile[s][c4 * 4 + j];
    *(f32x4*)(out + ((size_t)(n * SITES + st * 128 + s) * XD + xq * 16 + c4 * 4)) = o;
  }
}

extern "C" void kernel_launch(void* const* d_in, const int* in_sizes, int n_in,
                              void* d_out, int out_size, void* d_ws, size_t ws_size,
                              hipStream_t stream) {
  const float* r  = (const float*)d_in[0];
  const float* u  = (const float*)d_in[1];
  const float* v  = (const float*)d_in[2];
  const float* w1 = (const float*)d_in[3];
  const float* w2 = (const float*)d_in[4];
  float* out = (float*)d_out;
  char* ws = (char*)d_ws;
  u16* at     = (u16*)(ws);                         // 8 MB  bf16 a, [n][r][h][v]
  u16* w2t    = (u16*)(ws + ((size_t)8 << 20));     // 1 MB  bf16 w2 [r][x][h]
  float* rt   = (float*)(ws + ((size_t)9 << 20));   // 2 MB  fp32 r [n][r][s]
  float* pbuf = (float*)(ws + ((size_t)19 << 20));  // 16 MB fp32 out-partials [rc][n][st][x][s]

  hipLaunchKernelGGL(k_a_full, dim3(896), dim3(512), 0, stream, w1, u, at, w2, w2t, r, rt);
  hipLaunchKernelGGL(k_main, dim3(512), dim3(256), 0, stream, v, at, w2t, rt, pbuf);
  hipLaunchKernelGGL(k_reduce, dim3(256), dim3(256), 0, stream, pbuf, out);
}